// Round 3
// baseline (75.257 us; speedup 1.0000x reference)
//
#include <hip/hip_runtime.h>

#define SCOPE_AGENT __HIP_MEMORY_SCOPE_AGENT

// ws layout (floats): psum[256] | pmn[256] | pmx[256] | pcnt[256](int)
//                     | flags1[256](uint) | flags2[256](uint)
// No init required: flags use MAGIC values; slots are only read after the
// corresponding flag is observed (release/acquire device-scope atomics).

__global__ __launch_bounds__(256) void SPL_one(const float* __restrict__ pred,
                                               const float* __restrict__ tgt,
                                               float* __restrict__ ws,
                                               float* __restrict__ out) {
    __shared__ float sP[1280], sT[1280];   // 10 rows x 128 cols, zero-padded
    __shared__ float vsP[256], vsT[256];   // vertical 9-sums
    __shared__ float red[12];
    __shared__ int   redi[4];
    __shared__ float bcast[2];

    float*    psum   = ws;
    float*    pmn    = ws + 256;
    float*    pmx    = ws + 512;
    int*      pcnt   = (int*)(ws + 768);
    unsigned* flags1 = (unsigned*)(ws + 1024);
    unsigned* flags2 = (unsigned*)(ws + 1280);
    const unsigned MAGIC1 = 0xA11C0DE5u;
    const unsigned MAGIC2 = 0x5EC0DE22u;

    int b = blockIdx.x;
    int t = threadIdx.x;
    int m  = b >> 6;              // image 0..3
    int r2 = (b & 63) << 1;       // first of the 2 output rows
    const float* p = pred + (m << 14);
    const float* q = tgt  + (m << 14);

    // ---- phase 1: box-mean distortion + per-block wmse/min/max (identical math) ----
#pragma unroll
    for (int s = 0; s < 5; ++s) {
        int k   = t + s * 256;    // 0..1279
        int rr  = k >> 7;
        int cc  = k & 127;
        int grw = r2 - 4 + rr;
        bool ok = (unsigned)grw < 128u;
        sP[k] = ok ? p[(grw << 7) + cc] : 0.f;
        sT[k] = ok ? q[(grw << 7) + cc] : 0.f;
    }
    __syncthreads();

    int orow = t >> 7;            // 0/1
    int col  = t & 127;
    int row  = r2 + orow;

    float vp = 0.f, vt = 0.f;
    int vb = orow * 128 + col;
#pragma unroll
    for (int di = 0; di < 9; ++di) {
        vp += sP[vb + di * 128];
        vt += sT[vb + di * 128];
    }
    vsP[t] = vp; vsT[t] = vt;
    __syncthreads();

    float sp = 0.f, st = 0.f;
    int rbase = t & ~127;
#pragma unroll
    for (int dj = -4; dj <= 4; ++dj) {
        int jj = col + dj;
        if ((unsigned)jj < 128u) { sp += vsP[rbase + jj]; st += vsT[rbase + jj]; }
    }

    int   rc  = min(row, 4) + min(127 - row, 4) + 1;
    int   cn  = min(col, 4) + min(127 - col, 4) + 1;
    float den = (float)(rc * cn);
    float pv  = sP[(orow + 4) * 128 + col];
    float tv  = sT[(orow + 4) * 128 + col];
    float pd  = pv - sp / den;    // live across the grid barrier, in registers
    float td  = tv - st / den;

    // threshold-weighted MSE term
    float w = 1.f;
    if (tv >= 0.5f) w = 2.f;
    if (tv >= 2.f)  w = 5.f;
    if (tv >= 5.f)  w = 10.f;
    if (tv >= 10.f) w = 30.f;
    float d  = pv - tv;
    float s  = w * d * d;
    float mn = fminf(pd, td);
    float mx = fmaxf(pd, td);

    for (int o = 32; o > 0; o >>= 1) {
        s  += __shfl_down(s, o, 64);
        mn  = fminf(mn, __shfl_down(mn, o, 64));
        mx  = fmaxf(mx, __shfl_down(mx, o, 64));
    }
    int lane = t & 63, wid = t >> 6;
    if (lane == 0) { red[wid] = s; red[4 + wid] = mn; red[8 + wid] = mx; }
    __syncthreads();
    if (t == 0) {
        float bs  = red[0] + red[1] + red[2] + red[3];
        float bmn = fminf(fminf(red[4], red[5]), fminf(red[6], red[7]));
        float bmx = fmaxf(fmaxf(red[8], red[9]), fmaxf(red[10], red[11]));
        __hip_atomic_store(&psum[b], bs,  __ATOMIC_RELAXED, SCOPE_AGENT);
        __hip_atomic_store(&pmn[b],  bmn, __ATOMIC_RELAXED, SCOPE_AGENT);
        __hip_atomic_store(&pmx[b],  bmx, __ATOMIC_RELAXED, SCOPE_AGENT);
        __hip_atomic_store(&flags1[b], MAGIC1, __ATOMIC_RELEASE, SCOPE_AGENT);
    }

    // ---- hand-rolled grid barrier: wave 0 polls all 256 arrival flags ----
    if (t < 64) {
        for (int i = t; i < 256; i += 64) {
            while (__hip_atomic_load(&flags1[i], __ATOMIC_ACQUIRE, SCOPE_AGENT) != MAGIC1)
                __builtin_amdgcn_s_sleep(1);
        }
    }
    __syncthreads();

    // ---- phase 2: redundant per-block lo/hi reduction over slots, then count ----
    float mn2 = __hip_atomic_load(&pmn[t], __ATOMIC_RELAXED, SCOPE_AGENT);
    float mx2 = __hip_atomic_load(&pmx[t], __ATOMIC_RELAXED, SCOPE_AGENT);
    for (int o = 32; o > 0; o >>= 1) {
        mn2 = fminf(mn2, __shfl_down(mn2, o, 64));
        mx2 = fmaxf(mx2, __shfl_down(mx2, o, 64));
    }
    if (lane == 0) { red[4 + wid] = mn2; red[8 + wid] = mx2; }
    __syncthreads();
    if (t == 0) {
        bcast[0] = fminf(fminf(red[4], red[5]), fminf(red[6], red[7]));
        bcast[1] = fmaxf(fmaxf(red[8], red[9]), fmaxf(red[10], red[11]));
    }
    __syncthreads();
    float lo = bcast[0], hi = bcast[1];
    float dx = (hi - lo) / 999.0f;
    float inv_dx = 1.0f / dx;

    // per-pixel count of grid points x_k = lo + k*dx, k in [0,1000), inside [min,max)
    float a0 = fminf(pd, td);
    float b0 = fmaxf(pd, td);
    int ka = (int)ceilf((a0 - lo) * inv_dx);
    int kb = (int)ceilf((b0 - lo) * inv_dx);
    ka = max(ka, 0); kb = min(kb, 1000);
    int cnt = max(kb - ka, 0);

    for (int o = 32; o > 0; o >>= 1) cnt += __shfl_down(cnt, o, 64);
    if (lane == 0) redi[wid] = cnt;
    __syncthreads();
    if (t == 0) {
        int bc = redi[0] + redi[1] + redi[2] + redi[3];
        __hip_atomic_store(&pcnt[b], bc, __ATOMIC_RELAXED, SCOPE_AGENT);
        __hip_atomic_store(&flags2[b], MAGIC2, __ATOMIC_RELEASE, SCOPE_AGENT);
    }

    // ---- phase 3: block 0 waits for all count slots, folds, writes the loss ----
    if (b == 0) {
        if (t < 64) {
            for (int i = t; i < 256; i += 64) {
                while (__hip_atomic_load(&flags2[i], __ATOMIC_ACQUIRE, SCOPE_AGENT) != MAGIC2)
                    __builtin_amdgcn_s_sleep(1);
            }
        }
        __syncthreads();

        int   c  = __hip_atomic_load(&pcnt[t], __ATOMIC_RELAXED, SCOPE_AGENT);
        float ss = __hip_atomic_load(&psum[t], __ATOMIC_RELAXED, SCOPE_AGENT);
        for (int o = 32; o > 0; o >>= 1) {
            c  += __shfl_down(c, o, 64);
            ss += __shfl_down(ss, o, 64);
        }
        if (lane == 0) { redi[wid] = c; red[wid] = ss; }
        __syncthreads();
        if (t == 0) {
            long long tot = (long long)redi[0] + redi[1] + redi[2] + redi[3];
            float  wmse = (red[0] + red[1] + red[2] + red[3]) * (1.0f / 65536.0f);
            double crps = (double)tot * (double)dx / 65536.0;
            out[0] = 1e-4f * wmse + (float)crps;
        }
    }
}

extern "C" void kernel_launch(void* const* d_in, const int* in_sizes, int n_in,
                              void* d_out, int out_size, void* d_ws, size_t ws_size,
                              hipStream_t stream) {
    const float* pred = (const float*)d_in[0];
    const float* tgt  = (const float*)d_in[1];
    float* ws  = (float*)d_ws;     // 6 KB of slot/flag arrays, init-free protocol
    float* out = (float*)d_out;

    SPL_one<<<256, 256, 0, stream>>>(pred, tgt, ws, out);
}

// Round 4
// 74.574 us; speedup vs baseline: 1.0092x; 1.0092x over previous
//
#include <hip/hip_runtime.h>

#define SCOPE_AGENT __HIP_MEMORY_SCOPE_AGENT

// ws float layout (init-free MAGIC-flag protocol; slots read only after flag observed):
// [0..255]     psum   (plain stores, published by flags1/flags2 release)
// [256..511]   pmn
// [512..767]   pmx
// [768..1023]  pcnt (int)
// [1024..1279] flags1 (uint MAGIC1)  -- phase-1 arrival
// [1280..1535] flags2 (uint MAGIC2)  -- phase-2 arrival
// [1536..1791] go mirrors: goarr[x*32], x=0..7 (uint MAGICG), one per 128B line
// [1792..1793] lohi (float lo, hi)

__global__ __launch_bounds__(256) void SPL_one(const float* __restrict__ pred,
                                               const float* __restrict__ tgt,
                                               float* __restrict__ ws,
                                               float* __restrict__ out) {
    __shared__ float sP[1280], sT[1280];   // 10 rows x 128 cols, zero-padded
    __shared__ float vsP[256], vsT[256];   // vertical 9-sums
    __shared__ float red[12];
    __shared__ int   redi[4];
    __shared__ float bcast[2];

    float*    psum   = ws;
    float*    pmn    = ws + 256;
    float*    pmx    = ws + 512;
    int*      pcnt   = (int*)(ws + 768);
    unsigned* flags1 = (unsigned*)(ws + 1024);
    unsigned* flags2 = (unsigned*)(ws + 1280);
    unsigned* goarr  = (unsigned*)(ws + 1536);
    float*    lohi   = ws + 1792;
    const unsigned MAGIC1 = 0xA11C0DE5u;
    const unsigned MAGIC2 = 0x5EC0DE22u;
    const unsigned MAGICG = 0x60F1A600u;
    const int DETECTOR = 255;

    int b = blockIdx.x;
    int t = threadIdx.x;
    int m  = b >> 6;              // image 0..3
    int r2 = (b & 63) << 1;       // first of the 2 output rows
    const float* p = pred + (m << 14);
    const float* q = tgt  + (m << 14);

    // ---- phase 1: box-mean distortion + per-block wmse/min/max (identical math) ----
#pragma unroll
    for (int s = 0; s < 5; ++s) {
        int k   = t + s * 256;    // 0..1279
        int rr  = k >> 7;
        int cc  = k & 127;
        int grw = r2 - 4 + rr;
        bool ok = (unsigned)grw < 128u;
        sP[k] = ok ? p[(grw << 7) + cc] : 0.f;
        sT[k] = ok ? q[(grw << 7) + cc] : 0.f;
    }
    __syncthreads();

    int orow = t >> 7;            // 0/1
    int col  = t & 127;
    int row  = r2 + orow;

    float vp = 0.f, vt = 0.f;
    int vb = orow * 128 + col;
#pragma unroll
    for (int di = 0; di < 9; ++di) {
        vp += sP[vb + di * 128];
        vt += sT[vb + di * 128];
    }
    vsP[t] = vp; vsT[t] = vt;
    __syncthreads();

    float sp = 0.f, st = 0.f;
    int rbase = t & ~127;
#pragma unroll
    for (int dj = -4; dj <= 4; ++dj) {
        int jj = col + dj;
        if ((unsigned)jj < 128u) { sp += vsP[rbase + jj]; st += vsT[rbase + jj]; }
    }

    int   rc  = min(row, 4) + min(127 - row, 4) + 1;
    int   cn  = min(col, 4) + min(127 - col, 4) + 1;
    float den = (float)(rc * cn);
    float pv  = sP[(orow + 4) * 128 + col];
    float tv  = sT[(orow + 4) * 128 + col];
    float pd  = pv - sp / den;    // live across the barrier, in registers
    float td  = tv - st / den;

    float w = 1.f;
    if (tv >= 0.5f) w = 2.f;
    if (tv >= 2.f)  w = 5.f;
    if (tv >= 5.f)  w = 10.f;
    if (tv >= 10.f) w = 30.f;
    float d  = pv - tv;
    float s  = w * d * d;
    float mn = fminf(pd, td);
    float mx = fmaxf(pd, td);

    for (int o = 32; o > 0; o >>= 1) {
        s  += __shfl_down(s, o, 64);
        mn  = fminf(mn, __shfl_down(mn, o, 64));
        mx  = fmaxf(mx, __shfl_down(mx, o, 64));
    }
    int lane = t & 63, wid = t >> 6;
    if (lane == 0) { red[wid] = s; red[4 + wid] = mn; red[8 + wid] = mx; }
    __syncthreads();
    if (t == 0) {
        float bs  = red[0] + red[1] + red[2] + red[3];
        float bmn = fminf(fminf(red[4], red[5]), fminf(red[6], red[7]));
        float bmx = fmaxf(fmaxf(red[8], red[9]), fmaxf(red[10], red[11]));
        psum[b] = bs;             // plain stores, published by the release below
        pmn[b]  = bmn;
        pmx[b]  = bmx;
        __hip_atomic_store(&flags1[b], MAGIC1, __ATOMIC_RELEASE, SCOPE_AGENT);
    }

    // ---- master-block barrier: block 255 detects arrival, folds lo/hi, publishes go ----
    float lo, hi;
    if (b == DETECTOR) {
        while (__hip_atomic_load(&flags1[t], __ATOMIC_RELAXED, SCOPE_AGENT) != MAGIC1)
            __builtin_amdgcn_s_sleep(1);
        __syncthreads();
        __builtin_amdgcn_fence(__ATOMIC_ACQUIRE, "agent");   // one inv, then cached loads
        float mn2 = pmn[t], mx2 = pmx[t];
        for (int o = 32; o > 0; o >>= 1) {
            mn2 = fminf(mn2, __shfl_down(mn2, o, 64));
            mx2 = fmaxf(mx2, __shfl_down(mx2, o, 64));
        }
        if (lane == 0) { red[4 + wid] = mn2; red[8 + wid] = mx2; }
        __syncthreads();
        if (t == 0) {
            float l = fminf(fminf(red[4], red[5]), fminf(red[6], red[7]));
            float h = fmaxf(fmaxf(red[8], red[9]), fmaxf(red[10], red[11]));
            lohi[0] = l; lohi[1] = h;
            bcast[0] = l; bcast[1] = h;
        }
        __syncthreads();          // lo/hi stores visible block-wide (and in L2)
        if (t < 8) {
            __builtin_amdgcn_fence(__ATOMIC_RELEASE, "agent");   // flush L2 -> MALL
            __hip_atomic_store(&goarr[t * 32], MAGICG, __ATOMIC_RELAXED, SCOPE_AGENT);
        }
        lo = bcast[0]; hi = bcast[1];
    } else {
        if (t == 0) {
            while (__hip_atomic_load(&goarr[(b & 7) * 32], __ATOMIC_RELAXED, SCOPE_AGENT) != MAGICG)
                __builtin_amdgcn_s_sleep(1);
        }
        __syncthreads();
        __builtin_amdgcn_fence(__ATOMIC_ACQUIRE, "agent");
        if (t == 0) { bcast[0] = lohi[0]; bcast[1] = lohi[1]; }
        __syncthreads();
        lo = bcast[0]; hi = bcast[1];
    }

    // ---- phase 2: per-pixel CRPS grid-point count (pd/td still in registers) ----
    float dx = (hi - lo) / 999.0f;
    float inv_dx = 1.0f / dx;
    float a0 = fminf(pd, td);
    float b0 = fmaxf(pd, td);
    int ka = (int)ceilf((a0 - lo) * inv_dx);
    int kb = (int)ceilf((b0 - lo) * inv_dx);
    ka = max(ka, 0); kb = min(kb, 1000);
    int cnt = max(kb - ka, 0);

    for (int o = 32; o > 0; o >>= 1) cnt += __shfl_down(cnt, o, 64);
    if (lane == 0) redi[wid] = cnt;
    __syncthreads();
    if (t == 0) {
        pcnt[b] = redi[0] + redi[1] + redi[2] + redi[3];   // plain store
        __hip_atomic_store(&flags2[b], MAGIC2, __ATOMIC_RELEASE, SCOPE_AGENT);
    }

    // ---- phase 3: block 0 waits for all count flags, folds, writes the loss ----
    if (b == 0) {
        while (__hip_atomic_load(&flags2[t], __ATOMIC_RELAXED, SCOPE_AGENT) != MAGIC2)
            __builtin_amdgcn_s_sleep(1);
        __syncthreads();
        __builtin_amdgcn_fence(__ATOMIC_ACQUIRE, "agent");
        int   c  = pcnt[t];       // plain cached loads
        float ss = psum[t];
        for (int o = 32; o > 0; o >>= 1) {
            c  += __shfl_down(c, o, 64);
            ss += __shfl_down(ss, o, 64);
        }
        if (lane == 0) { redi[wid] = c; red[wid] = ss; }
        __syncthreads();
        if (t == 0) {
            long long tot = (long long)redi[0] + redi[1] + redi[2] + redi[3];
            float  wmse = (red[0] + red[1] + red[2] + red[3]) * (1.0f / 65536.0f);
            double crps = (double)tot * (double)dx / 65536.0;
            out[0] = 1e-4f * wmse + (float)crps;
        }
    }
}

extern "C" void kernel_launch(void* const* d_in, const int* in_sizes, int n_in,
                              void* d_out, int out_size, void* d_ws, size_t ws_size,
                              hipStream_t stream) {
    const float* pred = (const float*)d_in[0];
    const float* tgt  = (const float*)d_in[1];
    float* ws  = (float*)d_ws;     // ~7.2 KB of slot/flag arrays, init-free protocol
    float* out = (float*)d_out;

    SPL_one<<<256, 256, 0, stream>>>(pred, tgt, ws, out);
}

// Round 5
// 74.555 us; speedup vs baseline: 1.0094x; 1.0002x over previous
//
#include <hip/hip_runtime.h>

#define SCOPE_AGENT __HIP_MEMORY_SCOPE_AGENT

// ws float layout (init-free MAGIC-flag protocol, poison-immune):
// [0..255]    psum   (plain stores, published by per-block release flag)
// [256..511]  pmn
// [512..767]  pmx
// [768..1023] flags1 (uint, MAGIC1 when block's phase-1 results are published)
// [1024..]    float2 dist[65536] (512 KB)
//
// Structure: 256 blocks run phase 1 and post a flag; 255 exit immediately
// (no waiting => no rendezvous hop, no deadlock risk); block 255 alone polls
// the flags, acquire-fences once, and computes lo/hi + CRPS count + wmse fold.

__global__ __launch_bounds__(256) void SPL_tk(const float* __restrict__ pred,
                                              const float* __restrict__ tgt,
                                              float* __restrict__ ws,
                                              float* __restrict__ out) {
    __shared__ float sP[1280], sT[1280];   // 10 rows x 128 cols, zero-padded
    __shared__ float vsP[256], vsT[256];   // vertical 9-sums
    __shared__ float red[12];
    __shared__ int   redi[4];

    float*    psum   = ws;
    float*    pmn    = ws + 256;
    float*    pmx    = ws + 512;
    unsigned* flags1 = (unsigned*)(ws + 768);
    float2*   dist   = (float2*)(ws + 1024);
    const unsigned MAGIC1 = 0xA11C0DE5u;
    const int DETECTOR = 255;

    int b = blockIdx.x;
    int t = threadIdx.x;
    int m  = b >> 6;              // image 0..3
    int r2 = (b & 63) << 1;       // first of the 2 output rows
    const float* p = pred + (m << 14);
    const float* q = tgt  + (m << 14);

    // ---- phase 1: box-mean distortion + per-block wmse/min/max (identical to R2 kA) ----
#pragma unroll
    for (int s = 0; s < 5; ++s) {
        int k   = t + s * 256;    // 0..1279
        int rr  = k >> 7;
        int cc  = k & 127;
        int grw = r2 - 4 + rr;
        bool ok = (unsigned)grw < 128u;
        sP[k] = ok ? p[(grw << 7) + cc] : 0.f;
        sT[k] = ok ? q[(grw << 7) + cc] : 0.f;
    }
    __syncthreads();

    int orow = t >> 7;            // 0/1
    int col  = t & 127;
    int row  = r2 + orow;

    float vp = 0.f, vt = 0.f;
    int vb = orow * 128 + col;
#pragma unroll
    for (int di = 0; di < 9; ++di) {
        vp += sP[vb + di * 128];
        vt += sT[vb + di * 128];
    }
    vsP[t] = vp; vsT[t] = vt;
    __syncthreads();

    float sp = 0.f, st = 0.f;
    int rbase = t & ~127;
#pragma unroll
    for (int dj = -4; dj <= 4; ++dj) {
        int jj = col + dj;
        if ((unsigned)jj < 128u) { sp += vsP[rbase + jj]; st += vsT[rbase + jj]; }
    }

    int   rc  = min(row, 4) + min(127 - row, 4) + 1;
    int   cn  = min(col, 4) + min(127 - col, 4) + 1;
    float den = (float)(rc * cn);
    float pv  = sP[(orow + 4) * 128 + col];
    float tv  = sT[(orow + 4) * 128 + col];
    float pd  = pv - sp / den;
    float td  = tv - st / den;

    dist[(b << 8) + t] = make_float2(pd, td);   // plain store, published by release below

    float w = 1.f;
    if (tv >= 0.5f) w = 2.f;
    if (tv >= 2.f)  w = 5.f;
    if (tv >= 5.f)  w = 10.f;
    if (tv >= 10.f) w = 30.f;
    float d  = pv - tv;
    float s  = w * d * d;
    float mn = fminf(pd, td);
    float mx = fmaxf(pd, td);

    for (int o = 32; o > 0; o >>= 1) {
        s  += __shfl_down(s, o, 64);
        mn  = fminf(mn, __shfl_down(mn, o, 64));
        mx  = fmaxf(mx, __shfl_down(mx, o, 64));
    }
    int lane = t & 63, wid = t >> 6;
    if (lane == 0) { red[wid] = s; red[4 + wid] = mn; red[8 + wid] = mx; }
    __syncthreads();
    if (t == 0) {
        psum[b] = red[0] + red[1] + red[2] + red[3];
        pmn[b]  = fminf(fminf(red[4], red[5]), fminf(red[6], red[7]));
        pmx[b]  = fmaxf(fmaxf(red[8], red[9]), fmaxf(red[10], red[11]));
        __hip_atomic_store(&flags1[b], MAGIC1, __ATOMIC_RELEASE, SCOPE_AGENT);
    }

    if (b != DETECTOR) return;    // 255 blocks exit: zero rendezvous cost

    // ---- detector: wait for all 256 publish flags (thread t polls flag t) ----
    while (__hip_atomic_load(&flags1[t], __ATOMIC_RELAXED, SCOPE_AGENT) != MAGIC1)
        __builtin_amdgcn_s_sleep(1);
    __syncthreads();
    __builtin_amdgcn_fence(__ATOMIC_ACQUIRE, "agent");   // one L1/L2 inv, then cached loads

    // ---- lo/hi fold over per-block partials (identical order to R2 kB2) ----
    float mn2 = pmn[t];
    float mx2 = pmx[t];
    for (int o = 32; o > 0; o >>= 1) {
        mn2 = fminf(mn2, __shfl_down(mn2, o, 64));
        mx2 = fmaxf(mx2, __shfl_down(mx2, o, 64));
    }
    if (lane == 0) { red[4 + wid] = mn2; red[8 + wid] = mx2; }
    __syncthreads();
    float lo = fminf(fminf(red[4], red[5]), fminf(red[6], red[7]));
    float hi = fmaxf(fmaxf(red[8], red[9]), fmaxf(red[10], red[11]));
    float dx = (hi - lo) / 999.0f;
    float inv_dx = 1.0f / dx;

    // ---- CRPS count over all 65536 pixels (2 px per float4, 128 iters) ----
    const float4* dist4 = (const float4*)dist;
    int cnt = 0;
#pragma unroll 8
    for (int it = 0; it < 128; ++it) {
        float4 dv = dist4[it * 256 + t];
        float a0 = fminf(dv.x, dv.y), b0 = fmaxf(dv.x, dv.y);
        float a1 = fminf(dv.z, dv.w), b1 = fmaxf(dv.z, dv.w);
        int ka0 = (int)ceilf((a0 - lo) * inv_dx);
        int kb0 = (int)ceilf((b0 - lo) * inv_dx);
        int ka1 = (int)ceilf((a1 - lo) * inv_dx);
        int kb1 = (int)ceilf((b1 - lo) * inv_dx);
        ka0 = max(ka0, 0); kb0 = min(kb0, 1000);
        ka1 = max(ka1, 0); kb1 = min(kb1, 1000);
        cnt += max(kb0 - ka0, 0) + max(kb1 - ka1, 0);
    }
    for (int o = 32; o > 0; o >>= 1) cnt += __shfl_down(cnt, o, 64);
    if (lane == 0) redi[wid] = cnt;

    // ---- wmse fold (identical order to R2 kB2) ----
    float ss = psum[t];
    for (int o = 32; o > 0; o >>= 1) ss += __shfl_down(ss, o, 64);
    if (lane == 0) red[wid] = ss;
    __syncthreads();

    if (t == 0) {
        long long tot = (long long)redi[0] + redi[1] + redi[2] + redi[3];
        float  wmse = (red[0] + red[1] + red[2] + red[3]) * (1.0f / 65536.0f);
        double crps = (double)tot * (double)dx / 65536.0;
        out[0] = 1e-4f * wmse + (float)crps;
    }
}

extern "C" void kernel_launch(void* const* d_in, const int* in_sizes, int n_in,
                              void* d_out, int out_size, void* d_ws, size_t ws_size,
                              hipStream_t stream) {
    const float* pred = (const float*)d_in[0];
    const float* tgt  = (const float*)d_in[1];
    float* ws  = (float*)d_ws;     // ~4 KB slots/flags + 512 KB dist, init-free protocol
    float* out = (float*)d_out;

    SPL_tk<<<256, 256, 0, stream>>>(pred, tgt, ws, out);
}

// Round 6
// 64.890 us; speedup vs baseline: 1.1598x; 1.1490x over previous
//
#include <hip/hip_runtime.h>

// ws layout: float wmse_part[256] | float mn_part[256] | float mx_part[256]
//            | int cnt_accum, ticket (at part+768) | pad | float2 dist[65536] (at part+1024)

__global__ __launch_bounds__(256) void SPL_kA(const float* __restrict__ pred,
                                              const float* __restrict__ tgt,
                                              float* __restrict__ part,
                                              float2* __restrict__ dist) {
    __shared__ __align__(16) float sP[1280], sT[1280];   // 10 rows x 128 cols, zero-padded
    __shared__ float vsP[256], vsT[256];                 // vertical 9-sums
    __shared__ float red[12];

    int b = blockIdx.x;
    int t = threadIdx.x;
    int m  = b >> 6;              // image 0..3
    int r2 = (b & 63) << 1;       // first of the 2 output rows
    const float4* p4 = (const float4*)(pred + (m << 14));
    const float4* q4 = (const float4*)(tgt  + (m << 14));

    // zero the kB accumulator/ticket (visible to kB via kernel boundary)
    if (b == 0 && t < 2) ((int*)(part + 768))[t] = 0;

    // stage rows r2-4 .. r2+5 as float4 (zero-pad out-of-image); 320 float4 per array
    float4 z4 = make_float4(0.f, 0.f, 0.f, 0.f);
#pragma unroll
    for (int s = 0; s < 2; ++s) {
        int fidx = t + s * 256;       // float4 slot 0..319
        if (fidx < 320) {
            int rr  = fidx >> 5;      // row 0..9
            int c4  = fidx & 31;      // float4 col 0..31
            int grw = r2 - 4 + rr;
            bool ok = (unsigned)grw < 128u;
            float4 a  = ok ? p4[(grw << 5) + c4] : z4;
            float4 bb = ok ? q4[(grw << 5) + c4] : z4;
            ((float4*)sP)[fidx] = a;
            ((float4*)sT)[fidx] = bb;
        }
    }
    __syncthreads();

    int orow = t >> 7;            // 0/1
    int col  = t & 127;
    int row  = r2 + orow;

    // vertical 9-sum
    float vp = 0.f, vt = 0.f;
    int vb = orow * 128 + col;
#pragma unroll
    for (int di = 0; di < 9; ++di) {
        vp += sP[vb + di * 128];
        vt += sT[vb + di * 128];
    }
    vsP[t] = vp; vsT[t] = vt;
    __syncthreads();

    // horizontal 9-sum with column bounds
    float sp = 0.f, st = 0.f;
    int rbase = t & ~127;
#pragma unroll
    for (int dj = -4; dj <= 4; ++dj) {
        int jj = col + dj;
        if ((unsigned)jj < 128u) { sp += vsP[rbase + jj]; st += vsT[rbase + jj]; }
    }

    int   rc  = min(row, 4) + min(127 - row, 4) + 1;
    int   cn  = min(col, 4) + min(127 - col, 4) + 1;
    float den = (float)(rc * cn);
    float pv  = sP[(orow + 4) * 128 + col];
    float tv  = sT[(orow + 4) * 128 + col];
    float pd  = pv - sp / den;
    float td  = tv - st / den;

    dist[(b << 8) + t] = make_float2(pd, td);

    // threshold-weighted MSE term
    float w = 1.f;
    if (tv >= 0.5f) w = 2.f;
    if (tv >= 2.f)  w = 5.f;
    if (tv >= 5.f)  w = 10.f;
    if (tv >= 10.f) w = 30.f;
    float d  = pv - tv;
    float s  = w * d * d;
    float mn = fminf(pd, td);
    float mx = fmaxf(pd, td);

    for (int o = 32; o > 0; o >>= 1) {
        s  += __shfl_down(s, o, 64);
        mn  = fminf(mn, __shfl_down(mn, o, 64));
        mx  = fmaxf(mx, __shfl_down(mx, o, 64));
    }
    int lane = t & 63, wid = t >> 6;
    if (lane == 0) { red[wid] = s; red[4 + wid] = mn; red[8 + wid] = mx; }
    __syncthreads();
    if (t == 0) {
        part[b]       = red[0] + red[1] + red[2] + red[3];
        part[256 + b] = fminf(fminf(red[4], red[5]), fminf(red[6], red[7]));
        part[512 + b] = fmaxf(fmaxf(red[8], red[9]), fmaxf(red[10], red[11]));
    }
}

// 256 blocks x 256 threads: parallel CRPS count + atomic ticket finish
__global__ __launch_bounds__(256) void SPL_kB2(const float* __restrict__ part,
                                               const float2* __restrict__ dist,
                                               int* __restrict__ ctrs,
                                               float* __restrict__ out) {
    __shared__ float red[12];
    __shared__ int   redi[4];
    __shared__ int   sh_last;

    int b = blockIdx.x, t = threadIdx.x;
    int lane = t & 63, wid = t >> 6;

    // redundant per-block global lo/hi reduction over kA partials (3 KB, L2-hit)
    float mn = part[256 + t];
    float mx = part[512 + t];
    for (int o = 32; o > 0; o >>= 1) {
        mn = fminf(mn, __shfl_down(mn, o, 64));
        mx = fmaxf(mx, __shfl_down(mx, o, 64));
    }
    if (lane == 0) { red[4 + wid] = mn; red[8 + wid] = mx; }
    __syncthreads();
    float lo = fminf(fminf(red[4], red[5]), fminf(red[6], red[7]));
    float hi = fmaxf(fmaxf(red[8], red[9]), fmaxf(red[10], red[11]));
    float dx = (hi - lo) / 999.0f;
    float inv_dx = 1.0f / dx;

    // count grid points x_k = lo + k*dx, k in [0,1000), inside [min,max) per pixel
    float2 dpx = dist[(b << 8) + t];
    float a0 = fminf(dpx.x, dpx.y);
    float b0 = fmaxf(dpx.x, dpx.y);
    int ka = (int)ceilf((a0 - lo) * inv_dx);
    int kb = (int)ceilf((b0 - lo) * inv_dx);
    ka = max(ka, 0); kb = min(kb, 1000);
    int cnt = max(kb - ka, 0);

    for (int o = 32; o > 0; o >>= 1) cnt += __shfl_down(cnt, o, 64);
    if (lane == 0) redi[wid] = cnt;
    __syncthreads();

    if (t == 0) {
        int bc = redi[0] + redi[1] + redi[2] + redi[3];
        atomicAdd(&ctrs[0], bc);          // device-scope, coherent
        __threadfence();                  // order cnt-add before ticket-add
        int my = atomicAdd(&ctrs[1], 1);
        sh_last = (my == 255) ? 1 : 0;
    }
    __syncthreads();

    if (sh_last) {
        // last block folds the wmse partials and writes the loss
        float s = part[t];
        for (int o = 32; o > 0; o >>= 1) s += __shfl_down(s, o, 64);
        if (lane == 0) red[wid] = s;
        __syncthreads();
        if (t == 0) {
            int tot = atomicAdd(&ctrs[0], 0);   // coherent read of final total
            float  wmse = (red[0] + red[1] + red[2] + red[3]) * (1.0f / 65536.0f);
            double crps = (double)tot * (double)dx / 65536.0;
            out[0] = 1e-4f * wmse + (float)crps;
        }
    }
}

extern "C" void kernel_launch(void* const* d_in, const int* in_sizes, int n_in,
                              void* d_out, int out_size, void* d_ws, size_t ws_size,
                              hipStream_t stream) {
    const float* pred = (const float*)d_in[0];
    const float* tgt  = (const float*)d_in[1];
    float*  part = (float*)d_ws;                 // 768 floats + 2 ints
    float2* dist = (float2*)(part + 1024);       // 65536 float2 = 512 KB
    int*    ctrs = (int*)(part + 768);
    float*  out  = (float*)d_out;

    SPL_kA<<<256, 256, 0, stream>>>(pred, tgt, part, dist);
    SPL_kB2<<<256, 256, 0, stream>>>(part, dist, ctrs, out);
}